// Round 9
// baseline (27.885 us; speedup 1.0000x reference)
//
#include <hip/hip_runtime.h>
#include <math.h>

#define NF 50
#define REC 52           // per-block record: 50 z + s + pad
#define NBLK 1024        // pass1 grid: 4 blocks/CU, all resident at (512,8)
#define LOG2E 1.44269504f

// DPP ctrl codes
#define DPP_QXOR1 0xB1   // quad_perm [1,0,3,2]
#define DPP_QXOR2 0x4E   // quad_perm [2,3,0,1]
#define DPP_HMIRR 0x141  // row_half_mirror (l <-> 7-l within each 8)
#define DPP_ROR8  0x128  // row_ror:8

__device__ __forceinline__ float dpp_add(float v, int ctrl) {
    float t;
    switch (ctrl) {  // ctrl must be an ICE for the builtin
      case DPP_QXOR1: t = __int_as_float(__builtin_amdgcn_update_dpp(0, __float_as_int(v), DPP_QXOR1, 0xF, 0xF, true)); break;
      case DPP_QXOR2: t = __int_as_float(__builtin_amdgcn_update_dpp(0, __float_as_int(v), DPP_QXOR2, 0xF, 0xF, true)); break;
      case DPP_HMIRR: t = __int_as_float(__builtin_amdgcn_update_dpp(0, __float_as_int(v), DPP_HMIRR, 0xF, 0xF, true)); break;
      default:        t = __int_as_float(__builtin_amdgcn_update_dpp(0, __float_as_int(v), DPP_ROR8,  0xF, 0xF, true)); break;
    }
    return v + t;
}

// Pass 1: 8 lanes per row. Lane l owns float2 slots l, l+8, l+16; slot 24
// (features 48,49) is lane 0's 4th load (lanes 1..7 re-read their slot-16
// line with zero weight -> uniform shape, ~free). score reduce = 3 DPP adds
// (xor1, xor2, half_mirror). z stays lane-private (features disjoint);
// epilogue ror8 merges the two 8-groups of each 16-lane row.
// ~40 live VGPRs -> (512,8) is safe: 8 waves/SIMD, 1024 blocks all resident.
__global__ __launch_bounds__(512, 8) void attn_pass1(
    const float* __restrict__ query, const float* __restrict__ ql_w,
    const float* __restrict__ qWp, float* __restrict__ ws,
    int T, int totalGroups)
{
    const float qW = qWp[0];
    const int tid = threadIdx.x;
    const int l   = tid & 7;                       // lane within 8-group
    const int g   = blockIdx.x * 64 + (tid >> 3);  // global group id (row stream)

    const float2 zf2 = make_float2(0.f, 0.f);
    float2 w0 = *(const float2*)(ql_w + 2 * l);
    float2 w1 = *(const float2*)(ql_w + 2 * (l + 8));
    float2 w2 = *(const float2*)(ql_w + 2 * (l + 16));
    float2 w3 = (l == 0) ? *(const float2*)(ql_w + 48) : zf2;
    const int d3 = (l == 0) ? 192 : 128;           // byte offset of 4th load from rp

    float sw  = (w0.x + w0.y) + (w1.x + w1.y) + (w2.x + w2.y) + (w3.x + w3.y);
    float saw = fabsf(w0.x) + fabsf(w0.y) + fabsf(w1.x) + fabsf(w1.y)
              + fabsf(w2.x) + fabsf(w2.y) + fabsf(w3.x) + fabsf(w3.y);
    sw  = dpp_add(dpp_add(dpp_add(sw,  DPP_QXOR1), DPP_QXOR2), DPP_HMIRR);
    saw = dpp_add(dpp_add(dpp_add(saw, DPP_QXOR1), DPP_QXOR2), DPP_HMIRR);
    const float M0  = (saw > 80.f) ? (saw - 80.f) : 0.f;   // overflow guard; 0 here
    const float c2  = 2.f * qW * LOG2E;
    const float K   = (sw - M0) * LOG2E;
    const float n2l = -2.f * LOG2E;

    float2 z0 = zf2, z1 = zf2, z2 = zf2, z3 = zf2;
    float se = 0.f;

    const int G = totalGroups;                     // NBLK*64 = 65536
    const char* rp = (const char*)(query + (size_t)g * NF) + (l << 3);
    const size_t step = (size_t)G * NF * sizeof(float);

    for (int row = g; row < T; row += G, rp += step) {
        float2 x0 = *(const float2*)(rp);
        float2 x1 = *(const float2*)(rp + 64);
        float2 x2 = *(const float2*)(rp + 128);
        float2 x3 = *(const float2*)(rp + d3);

        float p = 0.f, r;
        r = __builtin_amdgcn_rcpf(__builtin_amdgcn_exp2f(c2 * x0.x) + 1.f); p = fmaf(w0.x, r, p);
        r = __builtin_amdgcn_rcpf(__builtin_amdgcn_exp2f(c2 * x0.y) + 1.f); p = fmaf(w0.y, r, p);
        r = __builtin_amdgcn_rcpf(__builtin_amdgcn_exp2f(c2 * x1.x) + 1.f); p = fmaf(w1.x, r, p);
        r = __builtin_amdgcn_rcpf(__builtin_amdgcn_exp2f(c2 * x1.y) + 1.f); p = fmaf(w1.y, r, p);
        r = __builtin_amdgcn_rcpf(__builtin_amdgcn_exp2f(c2 * x2.x) + 1.f); p = fmaf(w2.x, r, p);
        r = __builtin_amdgcn_rcpf(__builtin_amdgcn_exp2f(c2 * x2.y) + 1.f); p = fmaf(w2.y, r, p);
        r = __builtin_amdgcn_rcpf(__builtin_amdgcn_exp2f(c2 * x3.x) + 1.f); p = fmaf(w3.x, r, p);
        r = __builtin_amdgcn_rcpf(__builtin_amdgcn_exp2f(c2 * x3.y) + 1.f); p = fmaf(w3.y, r, p);

        p = dpp_add(dpp_add(dpp_add(p, DPP_QXOR1), DPP_QXOR2), DPP_HMIRR);
        const float e = __builtin_amdgcn_exp2f(fmaf(p, n2l, K));

        se += e;
        z0.x = fmaf(e, x0.x, z0.x); z0.y = fmaf(e, x0.y, z0.y);
        z1.x = fmaf(e, x1.x, z1.x); z1.y = fmaf(e, x1.y, z1.y);
        z2.x = fmaf(e, x2.x, z2.x); z2.y = fmaf(e, x2.y, z2.y);
        z3.x = fmaf(e, x3.x, z3.x); z3.y = fmaf(e, x3.y, z3.y);
    }

    // Merge the two 8-groups within each 16-lane row (lanes l and l+8 own
    // identical slots for different row streams); results valid on lanes 0-7.
    z0.x = dpp_add(z0.x, DPP_ROR8); z0.y = dpp_add(z0.y, DPP_ROR8);
    z1.x = dpp_add(z1.x, DPP_ROR8); z1.y = dpp_add(z1.y, DPP_ROR8);
    z2.x = dpp_add(z2.x, DPP_ROR8); z2.y = dpp_add(z2.y, DPP_ROR8);
    z3.x = dpp_add(z3.x, DPP_ROR8); z3.y = dpp_add(z3.y, DPP_ROR8);
    se   = dpp_add(se,   DPP_ROR8);

    __shared__ float sz[32][REC];
    if ((tid & 15) < 8) {
        const int eidx = tid >> 4;                 // 0..31
        *(float2*)&sz[eidx][2 * l]        = z0;
        *(float2*)&sz[eidx][2 * (l + 8)]  = z1;
        *(float2*)&sz[eidx][2 * (l + 16)] = z2;
        if (l == 0) {
            *(float2*)&sz[eidx][48] = z3;
            sz[eidx][50] = se;
            sz[eidx][51] = 0.f;
        }
    }
    __syncthreads();

    if (tid < 51) {
        float acc = 0.f;
        #pragma unroll
        for (int h = 0; h < 32; ++h) acc += sz[h][tid];
        ws[(size_t)blockIdx.x * REC + tid] = acc;
    }
}

// Pass 2: plain sum of B records (50 z + s each), divide, store.
__global__ __launch_bounds__(1024) void attn_pass2(
    const float* __restrict__ ws, float* __restrict__ out, int B)
{
    __shared__ float zacc[16][REC];
    const int tid = threadIdx.x;
    const int w = tid >> 6, lane = tid & 63;

    if (lane < 51) {
        float acc = 0.f;
        int b = w;
        for (; b + 112 < B; b += 128) {
            acc += ws[(size_t)(b      ) * REC + lane]
                 + ws[(size_t)(b +  16) * REC + lane]
                 + ws[(size_t)(b +  32) * REC + lane]
                 + ws[(size_t)(b +  48) * REC + lane]
                 + ws[(size_t)(b +  64) * REC + lane]
                 + ws[(size_t)(b +  80) * REC + lane]
                 + ws[(size_t)(b +  96) * REC + lane]
                 + ws[(size_t)(b + 112) * REC + lane];
        }
        for (; b < B; b += 16)
            acc += ws[(size_t)b * REC + lane];
        zacc[w][lane] = acc;
    }
    __syncthreads();
    if (tid < NF) {
        float Z = 0.f, S = 0.f;
        #pragma unroll
        for (int h = 0; h < 16; ++h) { Z += zacc[h][tid]; S += zacc[h][50]; }
        out[tid] = Z / S;
    }
}

extern "C" void kernel_launch(void* const* d_in, const int* in_sizes, int n_in,
                              void* d_out, int out_size, void* d_ws, size_t ws_size,
                              hipStream_t stream) {
    const float* query = (const float*)d_in[0];
    const float* ql_w  = (const float*)d_in[1];
    const float* qW    = (const float*)d_in[2];
    float* out = (float*)d_out;
    float* ws  = (float*)d_ws;

    const int T = in_sizes[0] / NF;

    int B = NBLK;
    size_t need = (size_t)B * REC * sizeof(float);
    if (ws_size < need) {
        B = (int)(ws_size / (REC * sizeof(float)));
        if (B < 1) B = 1;
    }

    const int totalGroups = B * 64;
    hipLaunchKernelGGL(attn_pass1, dim3(B), dim3(512), 0, stream,
                       query, ql_w, qW, ws, T, totalGroups);
    hipLaunchKernelGGL(attn_pass2, dim3(1), dim3(1024), 0, stream,
                       ws, out, B);
}